// Round 2
// baseline (1088.762 us; speedup 1.0000x reference)
//
#include <hip/hip_runtime.h>
#include <cstdint>

// LoRA forward: out = x@W^T + (x@A)@B + bias, folded to one bf16 GEMM:
//   Weff[n][k] = W[n][k] + sum_r A[k][r]*B[r][n];  out = Xb @ Weff^T + bias
// x (16384,4096) fp32 -> bf16, W (4096,4096), A (4096,16), B (16,4096).
#define M_DIM 16384
#define K_DIM 4096
#define N_DIM 4096
#define RANK  16

// GEMM tile: 256(M) x 128(N), BK=64, 512 threads = 8 waves (4M x 2N).
// 3-deep LDS pipeline with counted vmcnt (never 0 in main loop).
#define BM 256
#define BN 128
#define BK 64
#define NT (K_DIM / BK)                 // 64 K-tiles

#define A_ELEMS (BM * BK)               // 16384 bf16 = 32 KB
#define B_ELEMS (BN * BK)               // 8192  bf16 = 16 KB
#define BUF_ELEMS (A_ELEMS + B_ELEMS)   // 24576 elems = 48 KB / buffer
#define LDS_ELEMS (3 * BUF_ELEMS)       // 73728 elems = 144 KB (3 buffers)

typedef __bf16 bf16x8 __attribute__((ext_vector_type(8)));
typedef float  f32x4  __attribute__((ext_vector_type(4)));

__device__ __forceinline__ uint16_t f2bf(float f) {
    union { float f; uint32_t u; } v; v.f = f;
    uint32_t u = v.u;
    return (uint16_t)((u + 0x7FFFu + ((u >> 16) & 1u)) >> 16);
}

// ---------------------------------------------------------------------------
// prep, split into two kernels so rocprof attributes time per stage.
// ---------------------------------------------------------------------------
#define CVT_GRID 2048
#define CVT_ITems (M_DIM * K_DIM / 8)    // 8388608 chunks of 8 floats

__global__ void cvt_kernel(const float* __restrict__ x, uint16_t* __restrict__ xb) {
    const size_t stride = (size_t)CVT_GRID * 256;
    for (size_t g = (size_t)blockIdx.x * 256 + threadIdx.x; g < (size_t)CVT_ITems; g += stride) {
        const float4* xv = (const float4*)x;
        float4 a = xv[2 * g];
        float4 b = xv[2 * g + 1];
        union { uint4 u; uint16_t h[8]; } p;
        p.h[0] = f2bf(a.x); p.h[1] = f2bf(a.y); p.h[2] = f2bf(a.z); p.h[3] = f2bf(a.w);
        p.h[4] = f2bf(b.x); p.h[5] = f2bf(b.y); p.h[6] = f2bf(b.z); p.h[7] = f2bf(b.w);
        ((uint4*)xb)[g] = p.u;
    }
}

__global__ void weff_kernel(const float* __restrict__ W, const float* __restrict__ A,
                            const float* __restrict__ B, uint16_t* __restrict__ wb) {
    const int n = blockIdx.x;
    __shared__ float bcol[RANK];
    if (threadIdx.x < RANK) bcol[threadIdx.x] = B[threadIdx.x * N_DIM + n];
    __syncthreads();
    float bc[RANK];
#pragma unroll
    for (int r = 0; r < RANK; r++) bc[r] = bcol[r];
    for (int k = threadIdx.x; k < K_DIM; k += 256) {
        const float4* ar = (const float4*)(A + (size_t)k * RANK);
        float acc = W[(size_t)n * K_DIM + k];
#pragma unroll
        for (int q = 0; q < 4; q++) {
            float4 a4 = ar[q];
            acc += a4.x * bc[4*q+0] + a4.y * bc[4*q+1] + a4.z * bc[4*q+2] + a4.w * bc[4*q+3];
        }
        wb[(size_t)n * K_DIM + k] = f2bf(acc);
    }
}

// ---------------------------------------------------------------------------
// GEMM: C[m][n] = sum_k Xb[m][k]*Wb[n][k] + bias[n]
// 3-buffer pipeline: compute tile T from buf[T%3], stage tile T+2 into
// buf[(T+2)%3] interleaved into the two K-half phases. One raw s_barrier +
// counted s_waitcnt vmcnt(6) per K-tile: tile T+1's loads stay in flight
// across the barrier (T4). XOR chunk swizzle (proven 0-conflict) kept.
// ---------------------------------------------------------------------------
__device__ __forceinline__ void gload_lds16(const void* g, void* l) {
    __builtin_amdgcn_global_load_lds(
        (const __attribute__((address_space(1))) void*)g,
        (__attribute__((address_space(3))) void*)l,
        16, 0, 0);
}

__global__ __launch_bounds__(512, 2)
void gemm_bt_bias(const uint16_t* __restrict__ Xb,   // M x K, row-major
                  const uint16_t* __restrict__ Wb,   // N x K, row-major
                  const float* __restrict__ bias,    // N
                  float* __restrict__ C) {           // M x N
    __shared__ uint16_t smem[LDS_ELEMS];

    const int tid  = threadIdx.x;
    const int wave = tid >> 6;
    const int lane = tid & 63;
    const int wm = wave >> 1;     // 0..3 -> M offset wm*64
    const int wn = wave & 1;      // 0..1 -> N offset wn*64
    const int m15 = lane & 15;
    const int kq  = lane >> 4;

    // Bijective XCD chunk swizzle (T1, m204): 2048 blocks, 2048%8==0.
    const int lin = blockIdx.y * gridDim.x + blockIdx.x;     // [0,2048)
    const int swz = (lin & 7) * (2048 / 8) + (lin >> 3);
    const int bn = (swz & 31) * BN;    // 32 N-tiles
    const int bm = (swz >> 5) * BM;    // 64 M-tiles

    // Staging: A tile = 2048 chunks of 16B (4/thread), B tile = 1024 (2/thread).
    // LDS dest lane-contiguous (c*16B) as global_load_lds requires; global
    // source chunk XOR-swizzled: qg = ql ^ (row&7).
    const uint16_t* aSrc[4]; int aDst[4];
    const uint16_t* bSrc[2]; int bDst[2];
#pragma unroll
    for (int s = 0; s < 4; s++) {
        const int c = tid + 512 * s;
        const int row = c >> 3, qg = (c & 7) ^ (row & 7);
        aSrc[s] = Xb + (size_t)(bm + row) * K_DIM + qg * 8;
        aDst[s] = c * 8;
    }
#pragma unroll
    for (int s = 0; s < 2; s++) {
        const int c = tid + 512 * s;
        const int row = c >> 3, qg = (c & 7) ^ (row & 7);
        bSrc[s] = Wb + (size_t)(bn + row) * K_DIM + qg * 8;
        bDst[s] = A_ELEMS + c * 8;
    }

    // Fragment ds_read offsets (elements), same XOR swizzle:
    int aoff[4][2], boff[4][2];
#pragma unroll
    for (int i = 0; i < 4; i++) {
        const int ra = wm * 64 + i * 16 + m15;
        const int rb = wn * 64 + i * 16 + m15;
#pragma unroll
        for (int h = 0; h < 2; h++) {
            const int kc = h * 4 + kq;
            aoff[i][h] = ra * BK + (kc ^ (ra & 7)) * 8;
            boff[i][h] = A_ELEMS + rb * BK + (kc ^ (rb & 7)) * 8;
        }
    }

    f32x4 acc[4][4];
    const f32x4 zero = {0.f, 0.f, 0.f, 0.f};
#pragma unroll
    for (int i = 0; i < 4; i++)
#pragma unroll
        for (int j = 0; j < 4; j++) acc[i][j] = zero;

    // Prologue: tile0 -> buf0 (6 loads), tile1 -> buf1 (6 loads); wait for the
    // oldest 6 (tile0) only — tile1 stays in flight across the barrier.
#pragma unroll
    for (int s = 0; s < 4; s++) gload_lds16(aSrc[s], &smem[aDst[s]]);
#pragma unroll
    for (int s = 0; s < 2; s++) gload_lds16(bSrc[s], &smem[bDst[s]]);
#pragma unroll
    for (int s = 0; s < 4; s++) gload_lds16(aSrc[s] + BK, &smem[BUF_ELEMS + aDst[s]]);
#pragma unroll
    for (int s = 0; s < 2; s++) gload_lds16(bSrc[s] + BK, &smem[BUF_ELEMS + bDst[s]]);
    asm volatile("s_waitcnt vmcnt(6) lgkmcnt(0)" ::: "memory");
    __builtin_amdgcn_s_barrier();
    __builtin_amdgcn_sched_barrier(0);

    int rbO = 0;                 // read buffer (tile T)
    int sbO = 2 * BUF_ELEMS;     // stage buffer (tile T+2)

#pragma unroll 1
    for (int T = 0; T < NT; ++T) {
        const bool st = (T + 2 < NT);
        const int kst = (T + 2) * BK;

        // ---- phase 0 (k 0..31) ----
        if (st) {
            gload_lds16(aSrc[0] + kst, &smem[sbO + aDst[0]]);
            gload_lds16(aSrc[1] + kst, &smem[sbO + aDst[1]]);
            gload_lds16(bSrc[0] + kst, &smem[sbO + bDst[0]]);
        }
        {
            bf16x8 af[4], bfr[4];
#pragma unroll
            for (int i = 0; i < 4; i++) af[i]  = *(const bf16x8*)&smem[rbO + aoff[i][0]];
#pragma unroll
            for (int j = 0; j < 4; j++) bfr[j] = *(const bf16x8*)&smem[rbO + boff[j][0]];
            __builtin_amdgcn_s_setprio(1);
#pragma unroll
            for (int i = 0; i < 4; i++)
#pragma unroll
                for (int j = 0; j < 4; j++)
                    acc[i][j] = __builtin_amdgcn_mfma_f32_16x16x32_bf16(af[i], bfr[j], acc[i][j], 0, 0, 0);
            __builtin_amdgcn_s_setprio(0);
        }

        // ---- phase 1 (k 32..63) ----
        if (st) {
            gload_lds16(aSrc[2] + kst, &smem[sbO + aDst[2]]);
            gload_lds16(aSrc[3] + kst, &smem[sbO + aDst[3]]);
            gload_lds16(bSrc[1] + kst, &smem[sbO + bDst[1]]);
        }
        {
            bf16x8 af[4], bfr[4];
#pragma unroll
            for (int i = 0; i < 4; i++) af[i]  = *(const bf16x8*)&smem[rbO + aoff[i][1]];
#pragma unroll
            for (int j = 0; j < 4; j++) bfr[j] = *(const bf16x8*)&smem[rbO + boff[j][1]];
            __builtin_amdgcn_s_setprio(1);
#pragma unroll
            for (int i = 0; i < 4; i++)
#pragma unroll
                for (int j = 0; j < 4; j++)
                    acc[i][j] = __builtin_amdgcn_mfma_f32_16x16x32_bf16(af[i], bfr[j], acc[i][j], 0, 0, 0);
            __builtin_amdgcn_s_setprio(0);
        }

        // ---- tile boundary: tile T+1 must be resident; keep tile T+2 in flight.
        if (T < NT - 1) {
            if (st) asm volatile("s_waitcnt vmcnt(6) lgkmcnt(0)" ::: "memory");
            else    asm volatile("s_waitcnt vmcnt(0) lgkmcnt(0)" ::: "memory");  // tail drain
            __builtin_amdgcn_s_barrier();
            __builtin_amdgcn_sched_barrier(0);
        }
        rbO += BUF_ELEMS; if (rbO == LDS_ELEMS) rbO = 0;
        sbO += BUF_ELEMS; if (sbO == LDS_ELEMS) sbO = 0;
    }

    // Epilogue: C/D layout col = lane&15, row = (lane>>4)*4 + reg  [m89/m91]
#pragma unroll
    for (int j = 0; j < 4; j++) {
        const int col = bn + wn * 64 + j * 16 + m15;
        const float bv = bias[col];
#pragma unroll
        for (int i = 0; i < 4; i++) {
            const int row0 = bm + wm * 64 + i * 16 + kq * 4;
#pragma unroll
            for (int r = 0; r < 4; r++) {
                C[(size_t)(row0 + r) * N_DIM + col] = acc[i][j][r] + bv;
            }
        }
    }
}

extern "C" void kernel_launch(void* const* d_in, const int* in_sizes, int n_in,
                              void* d_out, int out_size, void* d_ws, size_t ws_size,
                              hipStream_t stream) {
    const float* x    = (const float*)d_in[0];
    const float* A    = (const float*)d_in[1];
    const float* B    = (const float*)d_in[2];
    const float* W    = (const float*)d_in[3];
    const float* bias = (const float*)d_in[4];
    float* out = (float*)d_out;

    uint16_t* Xb = (uint16_t*)d_ws;
    uint16_t* Wb = (uint16_t*)((char*)d_ws + (size_t)M_DIM * K_DIM * sizeof(uint16_t));

    cvt_kernel<<<CVT_GRID, 256, 0, stream>>>(x, Xb);
    weff_kernel<<<N_DIM, 256, 0, stream>>>(W, A, B, Wb);

    dim3 grid(N_DIM / BN, M_DIM / BM);   // (32, 64) = 2048 blocks
    gemm_bt_bias<<<grid, 512, 0, stream>>>(Xb, Wb, bias, out);
}

// Round 5
// 982.335 us; speedup vs baseline: 1.1083x; 1.1083x over previous
//
#include <hip/hip_runtime.h>
#include <cstdint>

// LoRA forward: out = x@W^T + (x@A)@B + bias, folded to one bf16 GEMM:
//   Weff[n][k] = W[n][k] + sum_r A[k][r]*B[r][n];  out = Xb @ Weff^T + bias
#define M_DIM 16384
#define K_DIM 4096
#define N_DIM 4096
#define RANK  16

// 8-phase 256x256 tile, BK=64, 512 threads = 8 waves (2M x 4N), per-wave
// C = 128x64 (acc 8x4). LDS = plain double buffer (128 KB). Stage tile T+2
// into the CURRENT buffer after its reads complete: B in phase 3 (B reads
// dead at phase-2-end barrier), A in phase 4 (A reads dead at phase-3-end).
// Boundary s_waitcnt vmcnt(8) retires exactly tile T+1; 8 loads always in
// flight (T4 counted-vmcnt, never 0 in main loop). All barriers are
// asm-fenced (memory clobber) so no GL/ds_read crosses them (rule-18 class).
#define BM 256
#define BN 256
#define BK 64
#define NT (K_DIM / BK)                 // 64 K-tiles

#define HALF_ELEMS 8192                 // 128 rows x 64 cols bf16 = 16 KB
#define TILE_ELEMS (2 * HALF_ELEMS)     // 32 KB per matrix per tile
#define LDS_ELEMS  (4 * TILE_ELEMS)     // A[2 bufs] + B[2 bufs] = 128 KB
// Byte map: A buf0 [0,32768) A buf1 [32768,65536) B buf0 [65536,98304)
//           B buf1 [98304,131072)
#define B_BYTE_BASE 65536

typedef __bf16 bf16x8 __attribute__((ext_vector_type(8)));
typedef float  f32x4  __attribute__((ext_vector_type(4)));

__device__ __forceinline__ uint16_t f2bf(float f) {
    union { float f; uint32_t u; } v; v.f = f;
    uint32_t u = v.u;
    return (uint16_t)((u + 0x7FFFu + ((u >> 16) & 1u)) >> 16);
}

// ---------------------------------------------------------------------------
// Fused prep (round-0 proven): blocks [0,32768) convert x -> bf16;
// blocks [32768, 36864) build Weff -> bf16.
// ---------------------------------------------------------------------------
#define CVT_BLOCKS (M_DIM * K_DIM / (8 * 256))   // 32768

__global__ void prep_kernel(const float* __restrict__ x, uint16_t* __restrict__ xb,
                            const float* __restrict__ W, const float* __restrict__ A,
                            const float* __restrict__ B, uint16_t* __restrict__ wb) {
    if (blockIdx.x < CVT_BLOCKS) {
        size_t g = (size_t)blockIdx.x * blockDim.x + threadIdx.x;
        const float4* xv = (const float4*)x;
        float4 a = xv[2 * g];
        float4 b = xv[2 * g + 1];
        union { uint4 u; uint16_t h[8]; } p;
        p.h[0] = f2bf(a.x); p.h[1] = f2bf(a.y); p.h[2] = f2bf(a.z); p.h[3] = f2bf(a.w);
        p.h[4] = f2bf(b.x); p.h[5] = f2bf(b.y); p.h[6] = f2bf(b.z); p.h[7] = f2bf(b.w);
        ((uint4*)xb)[g] = p.u;
    } else {
        const int n = blockIdx.x - CVT_BLOCKS;
        __shared__ float bcol[RANK];
        if (threadIdx.x < RANK) bcol[threadIdx.x] = B[threadIdx.x * N_DIM + n];
        __syncthreads();
        float bc[RANK];
#pragma unroll
        for (int r = 0; r < RANK; r++) bc[r] = bcol[r];
        for (int k = threadIdx.x; k < K_DIM; k += blockDim.x) {
            const float4* ar = (const float4*)(A + (size_t)k * RANK);
            float acc = W[(size_t)n * K_DIM + k];
#pragma unroll
            for (int q = 0; q < 4; q++) {
                float4 a4 = ar[q];
                acc += a4.x * bc[4*q+0] + a4.y * bc[4*q+1] + a4.z * bc[4*q+2] + a4.w * bc[4*q+3];
            }
            wb[(size_t)n * K_DIM + k] = f2bf(acc);
        }
    }
}

// ---------------------------------------------------------------------------
// GEMM
// ---------------------------------------------------------------------------
#define GL(g, l) __builtin_amdgcn_global_load_lds( \
    (const __attribute__((address_space(1))) void*)(g), \
    (__attribute__((address_space(3))) void*)(l), 16, 0, 0)

#define MFMA1(d, a, b) (d) = __builtin_amdgcn_mfma_f32_16x16x32_bf16((a), (b), (d), 0, 0, 0)

// Barrier fused with a compiler memory fence: no memory op (GL / ds_read)
// may cross in issue order — makes the dead-slot staging proof robust.
#define BAR() asm volatile("s_barrier" ::: "memory")

__global__ __launch_bounds__(512, 2)
void gemm_bt_bias(const uint16_t* __restrict__ Xb,   // M x K, row-major
                  const uint16_t* __restrict__ Wb,   // N x K, row-major
                  const float* __restrict__ bias,    // N
                  float* __restrict__ C) {           // M x N
    __shared__ uint16_t smem[LDS_ELEMS];

    const int tid  = threadIdx.x;
    const int wave = tid >> 6;
    const int lane = tid & 63;
    const int wm  = wave >> 2;         // 0..1  -> M rows [wm*128, +128)
    const int wn  = wave & 3;          // 0..3  -> N cols [wn*64, +64)
    const int m15 = lane & 15;
    const int kq  = lane >> 4;
    const int r7  = m15 & 7;

    // Bijective XCD swizzle (1024 blocks, 1024%8==0): each XCD gets 8
    // consecutive bm panels x all bn; Xb bm-panel (2 MB) stays L2-resident.
    const int lin = blockIdx.y * gridDim.x + blockIdx.x;     // [0,1024)
    const int swz = (lin & 7) * 128 + (lin >> 3);
    const int bn = (swz & 15) * BN;
    const int bm = (swz >> 4) * BM;

    // Staging: half-tile = 128 rows x 128 B = 1024 chunks of 16B. Thread covers
    // chunks c0=tid (rows 0..63), c1=tid+512 (rows 64..127) per half. LDS dest
    // lane-contiguous (c*16B); global source chunk XOR-pre-swizzled.
    const int c0 = tid, c1 = tid + 512;
    const int sr0 = c0 >> 3, sr1 = c1 >> 3;
    const int sq0 = (c0 & 7) ^ (sr0 & 7), sq1 = (c1 & 7) ^ (sr1 & 7);
    const uint16_t* aS0 = Xb + (size_t)(bm + sr0) * K_DIM + sq0 * 8;
    const uint16_t* aS1 = Xb + (size_t)(bm + sr1) * K_DIM + sq1 * 8;
    const uint16_t* bS0 = Wb + (size_t)(bn + sr0) * K_DIM + sq0 * 8;
    const uint16_t* bS1 = Wb + (size_t)(bn + sr1) * K_DIM + sq1 * 8;
    const int dE0 = c0 * 8, dE1 = c1 * 8;        // elem offsets within a half
    const size_t hOF = (size_t)128 * K_DIM;      // half-1 source row offset

#define STAGE_A(bufe, kcol) do { \
        GL(aS0 + (kcol),       &smem[(bufe) + dE0]); \
        GL(aS1 + (kcol),       &smem[(bufe) + dE1]); \
        GL(aS0 + hOF + (kcol), &smem[(bufe) + HALF_ELEMS + dE0]); \
        GL(aS1 + hOF + (kcol), &smem[(bufe) + HALF_ELEMS + dE1]); \
    } while (0)
#define STAGE_B(bufe, kcol) do { \
        GL(bS0 + (kcol),       &smem[2 * TILE_ELEMS + (bufe) + dE0]); \
        GL(bS1 + (kcol),       &smem[2 * TILE_ELEMS + (bufe) + dE1]); \
        GL(bS0 + hOF + (kcol), &smem[2 * TILE_ELEMS + (bufe) + HALF_ELEMS + dE0]); \
        GL(bS1 + hOF + (kcol), &smem[2 * TILE_ELEMS + (bufe) + HALF_ELEMS + dE1]); \
    } while (0)

    // Fragment ds_read byte offsets within a half slot. Chunk kc = kh*4+kq is
    // stored at chunk (kc ^ (row&7)); row&7 == m15&7 (rows step by 16).
    // kh=1 address = kh=0 address ^ 64 (chunk XOR 4 -> byte XOR 64).
    const int aoff0 = m15 * 128 + ((kq ^ r7) << 4);
    const int aoff1 = aoff0 ^ 64;
    const int boff0 = ((wn & 1) * 64 + m15) * 128 + ((kq ^ r7) << 4);
    const int boff1 = boff0 ^ 64;

    f32x4 acc[8][4];
    const f32x4 zero = {0.f, 0.f, 0.f, 0.f};
#pragma unroll
    for (int i = 0; i < 8; i++)
#pragma unroll
        for (int j = 0; j < 4; j++) acc[i][j] = zero;

    // ---- Prologue: tile0 -> buf0, tile1 -> buf1; retire tile0 (oldest 8),
    // keep tile1's 8 in flight across the barrier.
    STAGE_A(0, 0); STAGE_B(0, 0);
    STAGE_A(TILE_ELEMS, BK); STAGE_B(TILE_ELEMS, BK);
    asm volatile("s_waitcnt vmcnt(8)" ::: "memory");
    BAR();
    __builtin_amdgcn_sched_barrier(0);

    const char* sbase = (const char*)smem;

#pragma unroll 1
    for (int T = 0; T < NT; ++T) {
        const int bufe = (T & 1) * TILE_ELEMS;           // elem base of read buf
        const bool st = (T + 2 < NT);
        const int kst = (T + 2) * BK;

        // per-wave read bases (BYTES): A buf at (T&1)*32768, B region base
        // 65536 + (T&1)*32768; wave picks its half.
        const char* pA = sbase + (T & 1) * 32768 + wm * 16384;
        const char* pB = sbase + B_BYTE_BASE + (T & 1) * 32768 + (wn >> 1) * 16384;

        bf16x8 aF[4][2], bF[4][2];

        // ===== phase 1: Q0 (M rows 0-63, N cols 0-31) — 12 ds_reads
#pragma unroll
        for (int i = 0; i < 4; i++) {
            aF[i][0] = *(const bf16x8*)(pA + i * 2048 + aoff0);
            aF[i][1] = *(const bf16x8*)(pA + i * 2048 + aoff1);
        }
#pragma unroll
        for (int j = 0; j < 2; j++) {
            bF[j][0] = *(const bf16x8*)(pB + j * 2048 + boff0);
            bF[j][1] = *(const bf16x8*)(pB + j * 2048 + boff1);
        }
        BAR();
        asm volatile("s_waitcnt lgkmcnt(0)" ::: "memory");
        __builtin_amdgcn_sched_barrier(0);
        __builtin_amdgcn_s_setprio(1);
#pragma unroll
        for (int i = 0; i < 4; i++)
#pragma unroll
            for (int j = 0; j < 2; j++) {
                MFMA1(acc[i][j], aF[i][0], bF[j][0]);
                MFMA1(acc[i][j], aF[i][1], bF[j][1]);
            }
        __builtin_amdgcn_s_setprio(0);
        BAR();

        // ===== phase 2: Q1 (M rows 0-63, N cols 32-63) — 4 ds_reads
#pragma unroll
        for (int j = 2; j < 4; j++) {
            bF[j][0] = *(const bf16x8*)(pB + j * 2048 + boff0);
            bF[j][1] = *(const bf16x8*)(pB + j * 2048 + boff1);
        }
        BAR();
        asm volatile("s_waitcnt lgkmcnt(0)" ::: "memory");
        __builtin_amdgcn_sched_barrier(0);
        __builtin_amdgcn_s_setprio(1);
#pragma unroll
        for (int i = 0; i < 4; i++)
#pragma unroll
            for (int j = 0; j < 2; j++) {
                MFMA1(acc[i][2 + j], aF[i][0], bF[2 + j][0]);
                MFMA1(acc[i][2 + j], aF[i][1], bF[2 + j][1]);
            }
        __builtin_amdgcn_s_setprio(0);
        BAR();
        // All waves' B reads of tile T retired before the barrier above
        // (each wave's lgkmcnt(0) preceded its MFMAs) -> B slots dead.

        // ===== phase 3: Q2 (M rows 64-127, N cols 32-63) — 8 ds_reads,
        // stage B(T+2) into current (dead) B slots.
#pragma unroll
        for (int i = 0; i < 4; i++) {
            aF[i][0] = *(const bf16x8*)(pA + (4 + i) * 2048 + aoff0);
            aF[i][1] = *(const bf16x8*)(pA + (4 + i) * 2048 + aoff1);
        }
        if (st) STAGE_B(bufe, kst);
        BAR();
        asm volatile("s_waitcnt lgkmcnt(0)" ::: "memory");
        __builtin_amdgcn_sched_barrier(0);
        __builtin_amdgcn_s_setprio(1);
#pragma unroll
        for (int i = 0; i < 4; i++)
#pragma unroll
            for (int j = 0; j < 2; j++) {
                MFMA1(acc[4 + i][2 + j], aF[i][0], bF[2 + j][0]);
                MFMA1(acc[4 + i][2 + j], aF[i][1], bF[2 + j][1]);
            }
        __builtin_amdgcn_s_setprio(0);
        BAR();
        // A reads of tile T retired before this barrier -> A slots dead.

        // ===== phase 4: Q3 (M rows 64-127, N cols 0-31) — 0 ds_reads,
        // stage A(T+2); MFMA first (register-only), then counted boundary wait.
        if (st) STAGE_A(bufe, kst);
        __builtin_amdgcn_s_setprio(1);
#pragma unroll
        for (int i = 0; i < 4; i++)
#pragma unroll
            for (int j = 0; j < 2; j++) {
                MFMA1(acc[4 + i][j], aF[i][0], bF[j][0]);
                MFMA1(acc[4 + i][j], aF[i][1], bF[j][1]);
            }
        __builtin_amdgcn_s_setprio(0);
        if (T < NT - 1) {
            // outstanding: 8 (T+1) + 8 (T+2 if staged). Retire T+1 exactly;
            // over-waiting (if compiler injected VMEM) is safe by FIFO order.
            if (st) asm volatile("s_waitcnt vmcnt(8)" ::: "memory");
            else    asm volatile("s_waitcnt vmcnt(0)" ::: "memory");  // T=NT-2
            BAR();
            __builtin_amdgcn_sched_barrier(0);
        }
    }

    // Epilogue: C/D layout col = lane&15, row = (lane>>4)*4 + reg  [m89/m91]
#pragma unroll
    for (int j = 0; j < 4; j++) {
        const int col = bn + wn * 64 + j * 16 + m15;
        const float bv = bias[col];
#pragma unroll
        for (int i = 0; i < 8; i++) {
            const int row0 = bm + wm * 128 + i * 16 + kq * 4;
#pragma unroll
            for (int r = 0; r < 4; r++) {
                C[(size_t)(row0 + r) * N_DIM + col] = acc[i][j][r] + bv;
            }
        }
    }
}

extern "C" void kernel_launch(void* const* d_in, const int* in_sizes, int n_in,
                              void* d_out, int out_size, void* d_ws, size_t ws_size,
                              hipStream_t stream) {
    const float* x    = (const float*)d_in[0];
    const float* A    = (const float*)d_in[1];
    const float* B    = (const float*)d_in[2];
    const float* W    = (const float*)d_in[3];
    const float* bias = (const float*)d_in[4];
    float* out = (float*)d_out;

    uint16_t* Xb = (uint16_t*)d_ws;
    uint16_t* Wb = (uint16_t*)((char*)d_ws + (size_t)M_DIM * K_DIM * sizeof(uint16_t));

    prep_kernel<<<CVT_BLOCKS + N_DIM, 256, 0, stream>>>(x, Xb, W, A, B, Wb);

    dim3 grid(N_DIM / BN, M_DIM / BM);   // (16, 64) = 1024 blocks
    gemm_bt_bias<<<grid, 512, 0, stream>>>(Xb, Wb, bias, out);
}